// Round 3
// baseline (151.134 us; speedup 1.0000x reference)
//
#include <hip/hip_runtime.h>
#include <hip/hip_bf16.h>

// GCN layer: out = scatter_add(edge_val * (x @ W^T)[edge_col], edge_row) + bias
// N=50000, E=800000, D=128.
// R10: accgather with INT32 fixed-point LDS accumulation (native ds_add_u32 via
// atomicAdd(int*); R9's float __hip_atomic_fetch_add compiled to a CAS retry
// loop -> 650us + replay nondeterminism). Scale 2^21: |support|<=~5.5, worst
// node sum ~250 -> 2^29 << 2^31 (4x headroom), quant err 4.8e-7 << bf16 tol.
// Integer accumulation is exactly associative -> bit-deterministic replays.
// gemm+binpass stay fused (R8). ~95-105 us of dur_us is harness poison/restore
// (256 MiB ws fill ~44 us each) - not addressable.

constexpr int D     = 128;
constexpr int NPB   = 64;    // nodes per bucket (dstloc fits in 6 bits)
constexpr int CAP   = 2048;  // bucket capacity; mean load ~1024 (+32 sigma)
constexpr int C1    = 2048;  // edges per binpass block (391 blocks at E=800k)
constexpr int BT    = 1024;  // threads per accgather block
constexpr int NBMAX = 1024;  // max buckets (4 per thread in binpass scan)

// ---- helpers ----
__device__ inline unsigned int bf1(float f) {            // fp32 -> bf16 bits (RNE)
    unsigned int u = __float_as_uint(f);
    return (u + 0x7fffu + ((u >> 16) & 1u)) >> 16;
}
__device__ inline unsigned int cvt2(float a, float b) {  // packed HW cvt (RNE)
    __hip_bfloat162 h = __float22bfloat162_rn(float2{a, b});
    return *reinterpret_cast<unsigned int*>(&h);
}
__device__ inline float bflo(unsigned int u) { return __uint_as_float(u << 16); }
__device__ inline float bfhi(unsigned int u) { return __uint_as_float(u & 0xffff0000u); }

constexpr float FXS  = 2097152.0f;        // 2^21
constexpr float FXSI = 1.0f / 2097152.0f;

// ---- fused: blocks [0,bin_blocks) do edge binning; the rest do MFMA GEMM ----
// GEMM: supb[n][o] = bf16( sum_k x[n][k] * W[o][k] ), 16x16x32 MFMA.
// Each wave: 2 row-strips of 16 sharing every B-fragment; B converted from
// f32 W in-flight (W is 64KB, L2-resident after first touch).
__global__ __launch_bounds__(256) void fused_gemm_bin_kernel(
        const float* __restrict__ x, const float* __restrict__ W,
        const int* __restrict__ erow, const int* __restrict__ ecol,
        const float* __restrict__ eval,
        int* __restrict__ gcursor, int2* __restrict__ coarse,
        unsigned short* __restrict__ supb,
        int n_edges, int nb, int n_nodes, int bin_blocks) {
    if ((int)blockIdx.x < bin_blocks) {
        // ================= binpass (256 threads, C1=2048) =================
        __shared__ int bkcnt[NBMAX];
        __shared__ int bkoff[NBMAX];
        __shared__ int wsum[4];
        __shared__ int gbase[NBMAX];
        __shared__ unsigned short slotbk[C1];
        __shared__ int2 stage[C1];
        const int t = threadIdx.x;
        const int base = blockIdx.x * C1;
        const int m = min(C1, n_edges - base);

        for (int i = t; i < NBMAX; i += 256) bkcnt[i] = 0;
        __syncthreads();

        constexpr int EPT = C1 / 256;  // 8
        int  bk[EPT], rank[EPT];
        int2 pk[EPT];
#pragma unroll
        for (int j = 0; j < EPT; ++j) {
            int i = t + j * 256;                 // coalesced
            bk[j] = -1;
            if (i < m) {
                int e = base + i;
                int dst = erow[e];
                int b = dst / NPB;
                bk[j] = b;
                rank[j] = atomicAdd(&bkcnt[b], 1);
                pk[j] = make_int2(ecol[e] | ((dst & (NPB - 1)) << 20),
                                  __float_as_int(eval[e]));
            }
        }
        __syncthreads();

        // exclusive scan of bkcnt[0..NBMAX): 4 buckets/thread, 2 barriers
        {
            const int w = t >> 6, l = t & 63;
            const int b0 = 4 * t;
            int c0 = bkcnt[b0], c1 = bkcnt[b0 + 1];
            int c2 = bkcnt[b0 + 2], c3 = bkcnt[b0 + 3];
            int s = c0 + c1 + c2 + c3;
            int inc = s;                          // 64-lane inclusive scan
#pragma unroll
            for (int o = 1; o < 64; o <<= 1) {
                int u = __shfl_up(inc, o, 64);
                if (l >= o) inc += u;
            }
            if (l == 63) wsum[w] = inc;
            __syncthreads();
            if (t < 4) {                          // scan the 4 wave totals
                int v = wsum[t];
                int winc = v;
#pragma unroll
                for (int o = 1; o < 4; o <<= 1) {
                    int u = __shfl_up(winc, o, 4);
                    if (t >= o) winc += u;
                }
                wsum[t] = winc - v;               // exclusive wave prefix
            }
            __syncthreads();
            int p = inc - s + wsum[w];
            bkoff[b0]     = p;
            bkoff[b0 + 1] = p + c0;
            bkoff[b0 + 2] = p + c0 + c1;
            bkoff[b0 + 3] = p + c0 + c1 + c2;
        }
        __syncthreads();

        // place into stage (LDS scatter) + record slot->bucket
#pragma unroll
        for (int j = 0; j < EPT; ++j) {
            if (bk[j] >= 0) {
                int s2 = bkoff[bk[j]] + rank[j];
                stage[s2] = pk[j];
                slotbk[s2] = (unsigned short)bk[j];
            }
        }
        // reserve global runs: one atomic per non-empty bucket
        for (int i = t; i < nb; i += 256) {
            int c = bkcnt[i];
            gbase[i] = (c > 0) ? (i * CAP + atomicAdd(&gcursor[i], c)) : 0;
        }
        __syncthreads();

        // copy runs out (consecutive slots in a bucket -> consecutive addrs)
        for (int i = t; i < m; i += 256) {
            int b = slotbk[i];
            int p = gbase[b] + (i - bkoff[b]);
            if (p < (b + 1) * CAP) coarse[p] = stage[i];   // clamp: never hit
        }
    } else {
        // ================= GEMM (128 rows/block, 4 waves) =================
        using frag  = __attribute__((ext_vector_type(8))) short;
        using f32x4 = __attribute__((ext_vector_type(4))) float;
        union FU { uint4 u; frag f; };
        const int wv = threadIdx.x >> 6;
        const int lane = threadIdx.x & 63;
        const int mm = lane & 15, quad = lane >> 4;
        const int row0 = (blockIdx.x - bin_blocks) * 128 + wv * 32;
        const int r0 = min(row0 + mm, n_nodes - 1);
        const int r1 = min(row0 + 16 + mm, n_nodes - 1);

        frag a0[4], a1[4];
#pragma unroll
        for (int kf = 0; kf < 4; ++kf) {
            const float4* xp0 = (const float4*)(x + (size_t)r0 * D + kf * 32 + quad * 8);
            float4 p = xp0[0], q = xp0[1];
            FU t;
            t.u.x = cvt2(p.x, p.y); t.u.y = cvt2(p.z, p.w);
            t.u.z = cvt2(q.x, q.y); t.u.w = cvt2(q.z, q.w);
            a0[kf] = t.f;
            const float4* xp1 = (const float4*)(x + (size_t)r1 * D + kf * 32 + quad * 8);
            p = xp1[0]; q = xp1[1];
            t.u.x = cvt2(p.x, p.y); t.u.y = cvt2(p.z, p.w);
            t.u.z = cvt2(q.x, q.y); t.u.w = cvt2(q.z, q.w);
            a1[kf] = t.f;
        }

        f32x4 acc0[8], acc1[8];
#pragma unroll
        for (int ct = 0; ct < 8; ++ct) {
            acc0[ct] = (f32x4){0.f, 0.f, 0.f, 0.f};
            acc1[ct] = (f32x4){0.f, 0.f, 0.f, 0.f};
        }

#pragma unroll
        for (int ct = 0; ct < 8; ++ct) {
            const float* wrow = W + (size_t)(ct * 16 + mm) * D;
#pragma unroll
            for (int kf = 0; kf < 4; ++kf) {
                const float4* wp = (const float4*)(wrow + kf * 32 + quad * 8);
                float4 p = wp[0], q = wp[1];
                FU tb;
                tb.u.x = cvt2(p.x, p.y); tb.u.y = cvt2(p.z, p.w);
                tb.u.z = cvt2(q.x, q.y); tb.u.w = cvt2(q.z, q.w);
                frag b = tb.f;
                acc0[ct] = __builtin_amdgcn_mfma_f32_16x16x32_bf16(a0[kf], b, acc0[ct], 0, 0, 0);
                acc1[ct] = __builtin_amdgcn_mfma_f32_16x16x32_bf16(a1[kf], b, acc1[ct], 0, 0, 0);
            }
        }

#pragma unroll
        for (int ct = 0; ct < 8; ++ct) {
#pragma unroll
            for (int r = 0; r < 4; ++r) {
                int rr0 = row0 + quad * 4 + r;
                if (rr0 < n_nodes)
                    supb[(size_t)rr0 * D + ct * 16 + mm] = (unsigned short)bf1(acc0[ct][r]);
                int rr1 = row0 + 16 + quad * 4 + r;
                if (rr1 < n_nodes)
                    supb[(size_t)rr1 * D + ct * 16 + mm] = (unsigned short)bf1(acc1[ct][r]);
            }
        }
    }
}

// ---- pass 2: LDS int32 fixed-point accumulator gather (no sort, no float
// atomics). Each wave processes every 16th edge (4-deep unroll for ILP on the
// random supb row reads); lane c covers cols 2c,2c+1; native ds_add_u32.
__global__ __launch_bounds__(BT) void accgather_kernel(const int* __restrict__ gcursor,
                                                       const int2* __restrict__ coarse,
                                                       const unsigned short* __restrict__ supb,
                                                       const float* __restrict__ bias,
                                                       float* __restrict__ out,
                                                       int n_nodes) {
    __shared__ int  acc[NPB * D];       // 32 KB
    __shared__ int2 elist[CAP];         // 16 KB
    const int t = threadIdx.x;
    const int b = blockIdx.x;
    const int node0 = b * NPB;
    const int m = min(gcursor[b], CAP);
    const int2* src = coarse + (size_t)b * CAP;

    for (int i = t; i < NPB * D / 4; i += BT)
        ((int4*)acc)[i] = int4{0, 0, 0, 0};
    for (int i = t; i < m; i += BT) elist[i] = src[i];
    __syncthreads();

    const int wv = t >> 6;              // 0..15
    const int c  = t & 63;              // lane: covers cols 2c, 2c+1

    int e = wv;
    for (; e + 48 < m; e += 64) {       // 4 independent edges per macro-iter
        int2 d0 = elist[e], d1 = elist[e + 16], d2 = elist[e + 32], d3 = elist[e + 48];
        unsigned int u0 = ((const unsigned int*)(supb + ((size_t)(d0.x & 0xFFFFF) << 7)))[c];
        unsigned int u1 = ((const unsigned int*)(supb + ((size_t)(d1.x & 0xFFFFF) << 7)))[c];
        unsigned int u2 = ((const unsigned int*)(supb + ((size_t)(d2.x & 0xFFFFF) << 7)))[c];
        unsigned int u3 = ((const unsigned int*)(supb + ((size_t)(d3.x & 0xFFFFF) << 7)))[c];
        float v0 = __int_as_float(d0.y) * FXS, v1 = __int_as_float(d1.y) * FXS;
        float v2 = __int_as_float(d2.y) * FXS, v3 = __int_as_float(d3.y) * FXS;
        int* a0 = acc + ((d0.x >> 20) & 63) * D + 2 * c;
        int* a1 = acc + ((d1.x >> 20) & 63) * D + 2 * c;
        int* a2 = acc + ((d2.x >> 20) & 63) * D + 2 * c;
        int* a3 = acc + ((d3.x >> 20) & 63) * D + 2 * c;
        atomicAdd(a0,     __float2int_rn(bflo(u0) * v0));
        atomicAdd(a0 + 1, __float2int_rn(bfhi(u0) * v0));
        atomicAdd(a1,     __float2int_rn(bflo(u1) * v1));
        atomicAdd(a1 + 1, __float2int_rn(bfhi(u1) * v1));
        atomicAdd(a2,     __float2int_rn(bflo(u2) * v2));
        atomicAdd(a2 + 1, __float2int_rn(bfhi(u2) * v2));
        atomicAdd(a3,     __float2int_rn(bflo(u3) * v3));
        atomicAdd(a3 + 1, __float2int_rn(bfhi(u3) * v3));
    }
    for (; e < m; e += 16) {
        int2 d0 = elist[e];
        unsigned int u0 = ((const unsigned int*)(supb + ((size_t)(d0.x & 0xFFFFF) << 7)))[c];
        float v0 = __int_as_float(d0.y) * FXS;
        int* a0 = acc + ((d0.x >> 20) & 63) * D + 2 * c;
        atomicAdd(a0,     __float2int_rn(bflo(u0) * v0));
        atomicAdd(a0 + 1, __float2int_rn(bfhi(u0) * v0));
    }
    __syncthreads();

    // epilogue: acc*2^-21 + bias -> out (coalesced float4)
    const int nvalid = min(NPB, n_nodes - node0);
    for (int i = t; i < nvalid * (D / 4); i += BT) {
        int node = i >> 5;              // 32 float4 per node
        int q = i & 31;
        int4 a = ((const int4*)acc)[node * 32 + q];
        float4 bb = ((const float4*)bias)[q];
        float4 r{(float)a.x * FXSI + bb.x, (float)a.y * FXSI + bb.y,
                 (float)a.z * FXSI + bb.z, (float)a.w * FXSI + bb.w};
        ((float4*)(out + (size_t)(node0 + node) * D))[q] = r;
    }
}

// ---- fallback (oversized graphs / tiny ws): atomic path ----
__global__ __launch_bounds__(256) void init_out_kernel(float4* __restrict__ out4,
                                                       const float4* __restrict__ bias4,
                                                       int total4) {
    int i = blockIdx.x * 256 + threadIdx.x;
    if (i < total4) out4[i] = bias4[i & 31];
}

__global__ __launch_bounds__(256) void scatter_fb_kernel(const int* __restrict__ erow,
                                                         const int* __restrict__ ecol,
                                                         const float* __restrict__ eval,
                                                         const unsigned short* __restrict__ supb,
                                                         float* __restrict__ out,
                                                         int n_edges) {
    int e = blockIdx.x * 8 + (threadIdx.x >> 5);
    if (e >= n_edges) return;
    int lane = threadIdx.x & 31;
    int src = ecol[e], dst = erow[e];
    float v = eval[e];
    const unsigned short* sp = supb + (size_t)src * D + lane * 4;
    float* op = out + (size_t)dst * D + lane * 4;
#pragma unroll
    for (int j = 0; j < 4; ++j)
        atomicAdd(op + j, v * __uint_as_float(((unsigned)sp[j]) << 16));
}

static inline size_t align_up(size_t v, size_t a) { return (v + a - 1) & ~(a - 1); }

extern "C" void kernel_launch(void* const* d_in, const int* in_sizes, int n_in,
                              void* d_out, int out_size, void* d_ws, size_t ws_size,
                              hipStream_t stream) {
    const float* x    = (const float*)d_in[0];
    const int*   erow = (const int*)d_in[1];
    const int*   ecol = (const int*)d_in[2];
    const float* eval = (const float*)d_in[3];
    const float* W    = (const float*)d_in[4];
    const float* bias = (const float*)d_in[5];
    float* out = (float*)d_out;

    const int n_nodes = in_sizes[0] / D;
    const int n_edges = in_sizes[1];
    const int nb = (n_nodes + NPB - 1) / NPB;

    char* base = (char*)d_ws;
    size_t off = 0;
    unsigned short* supb = (unsigned short*)(base + off); off = align_up(off + (size_t)n_nodes * D * 2, 256);
    int*  gcursor = (int*)(base + off);  off = align_up(off + (size_t)nb * 4, 256);
    int2* coarse  = (int2*)(base + off); off = align_up(off + (size_t)nb * CAP * 8, 256);

    const bool fast = (n_nodes < (1 << 20)) && (nb <= NBMAX) && (off <= ws_size);
    const int gemm_blocks = (n_nodes + 127) / 128;
    const int bin_blocks = fast ? (n_edges + C1 - 1) / C1 : 0;

    if (fast)
        hipMemsetAsync(gcursor, 0, (size_t)nb * 4, stream);

    fused_gemm_bin_kernel<<<bin_blocks + gemm_blocks, 256, 0, stream>>>(
        x, W, erow, ecol, eval, gcursor, coarse, supb,
        n_edges, nb, n_nodes, bin_blocks);

    if (fast) {
        accgather_kernel<<<nb, BT, 0, stream>>>(
            gcursor, coarse, supb, bias, out, n_nodes);
    } else {
        int total4 = n_nodes * (D / 4);
        init_out_kernel<<<(total4 + 255) / 256, 256, 0, stream>>>(
            (float4*)out, (const float4*)bias, total4);
        scatter_fb_kernel<<<(n_edges + 7) / 8, 256, 0, stream>>>(
            erow, ecol, eval, supb, out, n_edges);
    }
}

// Round 4
// 137.378 us; speedup vs baseline: 1.1001x; 1.1001x over previous
//
#include <hip/hip_runtime.h>
#include <hip/hip_bf16.h>

// GCN layer: out = scatter_add(edge_val * (x @ W^T)[edge_col], edge_row) + bias
// N=50000, E=800000, D=128.
// R11: (1) revert pass-2 to R8 sortgather (R10 accgather was -6us: 4x load
// instruction count). (2) Fix the real bottleneck exposed by R10 counters:
// fused gemm branch was 45.9us at 1.2% MFMA / 6% VALU / 22% occ -- pure
// latency-bound (1.5 waves/SIMD, every wave re-reading 64KB f32 W from L2).
// Now: W staged once per block into LDS as bf16 (XOR-swizzled, conflict-free
// b128 access), 16-row waves (2x wave parallelism, 782 gemm blocks), explicit
// LDS union with the bin branch (32.8KB -> 4 blocks/CU).

constexpr int D     = 128;
constexpr int NPB   = 64;    // nodes per bucket (dstloc fits in 6 bits)
constexpr int CAP   = 2048;  // bucket capacity; mean load ~1024 (+32 sigma)
constexpr int C1    = 2048;  // edges per binpass block (391 blocks at E=800k)
constexpr int BT    = 1024;  // threads per sortgather block
constexpr int NBMAX = 1024;  // max buckets (4 per thread in binpass scan)

// ---- helpers ----
__device__ inline unsigned int bf1(float f) {            // fp32 -> bf16 bits (RNE)
    unsigned int u = __float_as_uint(f);
    return (u + 0x7fffu + ((u >> 16) & 1u)) >> 16;
}
__device__ inline unsigned int cvt2(float a, float b) {  // packed HW cvt (RNE)
    __hip_bfloat162 h = __float22bfloat162_rn(float2{a, b});
    return *reinterpret_cast<unsigned int*>(&h);
}
__device__ inline float bflo(unsigned int u) { return __uint_as_float(u << 16); }
__device__ inline float bfhi(unsigned int u) { return __uint_as_float(u & 0xffff0000u); }

// ---- LDS overlay: bin branch and gemm branch never coexist in a block ----
struct BinSmem {
    int bkcnt[NBMAX];
    int bkoff[NBMAX];
    int wsum[4];
    int gbase[NBMAX];
    unsigned short slotbk[C1];
    int2 stage[C1];
};
struct GemmSmem {
    uint4 wb[2048];   // W as bf16: [o(128)][chunk(16)], chunk idx ^= (o&7); 32 KB
};
union SmemU { BinSmem b; GemmSmem g; };

// ---- fused: blocks [0,bin_blocks) do edge binning; the rest do MFMA GEMM ----
__global__ __launch_bounds__(256) void fused_gemm_bin_kernel(
        const float* __restrict__ x, const float* __restrict__ W,
        const int* __restrict__ erow, const int* __restrict__ ecol,
        const float* __restrict__ eval,
        int* __restrict__ gcursor, int2* __restrict__ coarse,
        unsigned short* __restrict__ supb,
        int n_edges, int nb, int n_nodes, int bin_blocks) {
    __shared__ SmemU sm;
    const int t = threadIdx.x;
    if ((int)blockIdx.x < bin_blocks) {
        // ================= binpass (256 threads, C1=2048) =================
        const int base = blockIdx.x * C1;
        const int m = min(C1, n_edges - base);

        for (int i = t; i < NBMAX; i += 256) sm.b.bkcnt[i] = 0;
        __syncthreads();

        constexpr int EPT = C1 / 256;  // 8
        int  bk[EPT], rank[EPT];
        int2 pk[EPT];
#pragma unroll
        for (int j = 0; j < EPT; ++j) {
            int i = t + j * 256;                 // coalesced
            bk[j] = -1;
            if (i < m) {
                int e = base + i;
                int dst = erow[e];
                int b = dst / NPB;
                bk[j] = b;
                rank[j] = atomicAdd(&sm.b.bkcnt[b], 1);
                pk[j] = make_int2(ecol[e] | ((dst & (NPB - 1)) << 20),
                                  __float_as_int(eval[e]));
            }
        }
        __syncthreads();

        // exclusive scan of bkcnt[0..NBMAX): 4 buckets/thread, 2 barriers
        {
            const int w = t >> 6, l = t & 63;
            const int b0 = 4 * t;
            int c0 = sm.b.bkcnt[b0], c1 = sm.b.bkcnt[b0 + 1];
            int c2 = sm.b.bkcnt[b0 + 2], c3 = sm.b.bkcnt[b0 + 3];
            int s = c0 + c1 + c2 + c3;
            int inc = s;                          // 64-lane inclusive scan
#pragma unroll
            for (int o = 1; o < 64; o <<= 1) {
                int u = __shfl_up(inc, o, 64);
                if (l >= o) inc += u;
            }
            if (l == 63) sm.b.wsum[w] = inc;
            __syncthreads();
            if (t < 4) {                          // scan the 4 wave totals
                int v = sm.b.wsum[t];
                int winc = v;
#pragma unroll
                for (int o = 1; o < 4; o <<= 1) {
                    int u = __shfl_up(winc, o, 4);
                    if (t >= o) winc += u;
                }
                sm.b.wsum[t] = winc - v;          // exclusive wave prefix
            }
            __syncthreads();
            int p = inc - s + sm.b.wsum[w];
            sm.b.bkoff[b0]     = p;
            sm.b.bkoff[b0 + 1] = p + c0;
            sm.b.bkoff[b0 + 2] = p + c0 + c1;
            sm.b.bkoff[b0 + 3] = p + c0 + c1 + c2;
        }
        __syncthreads();

        // place into stage (LDS scatter) + record slot->bucket
#pragma unroll
        for (int j = 0; j < EPT; ++j) {
            if (bk[j] >= 0) {
                int s2 = sm.b.bkoff[bk[j]] + rank[j];
                sm.b.stage[s2] = pk[j];
                sm.b.slotbk[s2] = (unsigned short)bk[j];
            }
        }
        // reserve global runs: one atomic per non-empty bucket
        for (int i = t; i < nb; i += 256) {
            int c = sm.b.bkcnt[i];
            sm.b.gbase[i] = (c > 0) ? (i * CAP + atomicAdd(&gcursor[i], c)) : 0;
        }
        __syncthreads();

        // copy runs out (consecutive slots in a bucket -> consecutive addrs)
        for (int i = t; i < m; i += 256) {
            int b = sm.b.slotbk[i];
            int p = sm.b.gbase[b] + (i - sm.b.bkoff[b]);
            if (p < (b + 1) * CAP) coarse[p] = sm.b.stage[i];   // clamp: never hit
        }
    } else {
        // ====== GEMM: 64 rows/block, 4 waves x 16 rows, W staged in LDS ======
        using frag  = __attribute__((ext_vector_type(8))) short;
        using f32x4 = __attribute__((ext_vector_type(4))) float;
        union FU { uint4 u; frag f; };
        const int gb = blockIdx.x - bin_blocks;
        const int wv = t >> 6;
        const int lane = t & 63;
        const int mm = lane & 15, quad = lane >> 4;
        const int row0 = gb * 64 + wv * 16;
        const int r0 = min(row0 + mm, n_nodes - 1);

        // A-fragment loads issued first (independent of LDS staging)
        frag a[4];
#pragma unroll
        for (int kf = 0; kf < 4; ++kf) {
            const float4* xp = (const float4*)(x + (size_t)r0 * D + kf * 32 + quad * 8);
            float4 p = xp[0], q = xp[1];
            FU tu;
            tu.u.x = cvt2(p.x, p.y); tu.u.y = cvt2(p.z, p.w);
            tu.u.z = cvt2(q.x, q.y); tu.u.w = cvt2(q.z, q.w);
            a[kf] = tu.f;
        }

        // stage W (f32 -> bf16) into LDS, swizzled: chunk c -> row o=c>>4,
        // k16=c&15 stored at (o<<4) + (k16 ^ (o&7)). Write: 16 consecutive
        // threads cover one 512B W row (fully coalesced); ds_write_b128 hits
        // 8 lanes per 16B slot (uniform = conflict-free).
#pragma unroll
        for (int j = 0; j < 8; ++j) {
            int c = t + j * 256;
            int o = c >> 4, k16 = c & 15;
            const float4* wp = (const float4*)(W + (size_t)o * D + k16 * 8);
            float4 p = wp[0], q = wp[1];
            uint4 r;
            r.x = cvt2(p.x, p.y); r.y = cvt2(p.z, p.w);
            r.z = cvt2(q.x, q.y); r.w = cvt2(q.z, q.w);
            sm.g.wb[(o << 4) + (k16 ^ (o & 7))] = r;
        }
        __syncthreads();

        f32x4 acc[8];
#pragma unroll
        for (int ct = 0; ct < 8; ++ct) acc[ct] = (f32x4){0.f, 0.f, 0.f, 0.f};

#pragma unroll
        for (int ct = 0; ct < 8; ++ct) {
            const int o = ct * 16 + mm;          // o&7 == mm&7
#pragma unroll
            for (int kf = 0; kf < 4; ++kf) {
                FU bu;
                bu.u = sm.g.wb[(o << 4) + ((kf * 4 + quad) ^ (mm & 7))];
                acc[ct] = __builtin_amdgcn_mfma_f32_16x16x32_bf16(a[kf], bu.f, acc[ct], 0, 0, 0);
            }
        }

#pragma unroll
        for (int ct = 0; ct < 8; ++ct) {
#pragma unroll
            for (int r = 0; r < 4; ++r) {
                int rr = row0 + quad * 4 + r;
                if (rr < n_nodes)
                    supb[(size_t)rr * D + ct * 16 + mm] = (unsigned short)bf1(acc[ct][r]);
            }
        }
    }
}

// ---- pass 2: within-bucket exact sort in LDS + quarter-wave fused gather ----
__global__ __launch_bounds__(BT) void sortgather_kernel(const int* __restrict__ gcursor,
                                                        const int2* __restrict__ coarse,
                                                        const unsigned short* __restrict__ supb,
                                                        const float* __restrict__ bias,
                                                        float* __restrict__ out,
                                                        int n_nodes) {
    __shared__ int ncnt[NPB];
    __shared__ int noff[NPB];
    __shared__ int ncur[NPB];
    __shared__ int2 sorted[CAP];
    const int t = threadIdx.x;
    const int b = blockIdx.x;
    const int node0 = b * NPB;
    const int m = min(gcursor[b], CAP);
    const int2* src = coarse + (size_t)b * CAP;

    if (t < NPB) ncnt[t] = 0;
    __syncthreads();

    for (int i = t; i < m; i += BT)
        atomicAdd(&ncnt[(src[i].x >> 20) & (NPB - 1)], 1);
    __syncthreads();

    if (t < NPB) {                        // wave 0: 64-lane inclusive shuffle scan
        int v = ncnt[t];
        int inc = v;
        for (int o = 1; o < NPB; o <<= 1) {
            int u = __shfl_up(inc, o, 64);
            if (t >= o) inc += u;
        }
        noff[t] = inc - v;
        ncur[t] = inc - v;
    }
    __syncthreads();

    for (int i = t; i < m; i += BT) {     // place into sorted LDS slots
        int2 e = src[i];
        int dl = (e.x >> 20) & (NPB - 1);
        int p = atomicAdd(&ncur[dl], 1);
        sorted[p] = make_int2(e.x & 0xFFFFF, e.y);
    }
    __syncthreads();

    // gather: 64 quarter-waves <-> 64 nodes; 16 lanes x 8 cols (uint4 = 8 bf16)
    const int qw = t >> 4;               // dst-local node id, 0..63
    const int l16 = t & 15;              // lane within quarter-wave
    const int node = node0 + qw;
    if (node >= n_nodes) return;
    const int beg = noff[qw];
    const int end = beg + ncnt[qw];

    const float4* b4 = (const float4*)(bias + l16 * 8);
    float4 acc0 = b4[0], acc1 = b4[1];

    int e = beg;
    for (; e + 1 < end; e += 2) {
        int2 d0 = sorted[e], d1 = sorted[e + 1];   // quarter-wave broadcast reads
        uint4 u0 = *(const uint4*)(supb + (size_t)d0.x * D + l16 * 8);
        uint4 u1 = *(const uint4*)(supb + (size_t)d1.x * D + l16 * 8);
        float v0 = __int_as_float(d0.y), v1 = __int_as_float(d1.y);
        acc0.x += v0 * bflo(u0.x) + v1 * bflo(u1.x);
        acc0.y += v0 * bfhi(u0.x) + v1 * bfhi(u1.x);
        acc0.z += v0 * bflo(u0.y) + v1 * bflo(u1.y);
        acc0.w += v0 * bfhi(u0.y) + v1 * bfhi(u1.y);
        acc1.x += v0 * bflo(u0.z) + v1 * bflo(u1.z);
        acc1.y += v0 * bfhi(u0.z) + v1 * bfhi(u1.z);
        acc1.z += v0 * bflo(u0.w) + v1 * bflo(u1.w);
        acc1.w += v0 * bfhi(u0.w) + v1 * bfhi(u1.w);
    }
    if (e < end) {
        int2 d0 = sorted[e];
        uint4 u0 = *(const uint4*)(supb + (size_t)d0.x * D + l16 * 8);
        float v0 = __int_as_float(d0.y);
        acc0.x += v0 * bflo(u0.x); acc0.y += v0 * bfhi(u0.x);
        acc0.z += v0 * bflo(u0.y); acc0.w += v0 * bfhi(u0.y);
        acc1.x += v0 * bflo(u0.z); acc1.y += v0 * bfhi(u0.z);
        acc1.z += v0 * bflo(u0.w); acc1.w += v0 * bfhi(u0.w);
    }
    float4* o4 = (float4*)(out + (size_t)node * D + l16 * 8);
    o4[0] = acc0;
    o4[1] = acc1;
}

// ---- fallback (oversized graphs / tiny ws): atomic path ----
__global__ __launch_bounds__(256) void init_out_kernel(float4* __restrict__ out4,
                                                       const float4* __restrict__ bias4,
                                                       int total4) {
    int i = blockIdx.x * 256 + threadIdx.x;
    if (i < total4) out4[i] = bias4[i & 31];
}

__global__ __launch_bounds__(256) void scatter_fb_kernel(const int* __restrict__ erow,
                                                         const int* __restrict__ ecol,
                                                         const float* __restrict__ eval,
                                                         const unsigned short* __restrict__ supb,
                                                         float* __restrict__ out,
                                                         int n_edges) {
    int e = blockIdx.x * 8 + (threadIdx.x >> 5);
    if (e >= n_edges) return;
    int lane = threadIdx.x & 31;
    int src = ecol[e], dst = erow[e];
    float v = eval[e];
    const unsigned short* sp = supb + (size_t)src * D + lane * 4;
    float* op = out + (size_t)dst * D + lane * 4;
#pragma unroll
    for (int j = 0; j < 4; ++j)
        atomicAdd(op + j, v * __uint_as_float(((unsigned)sp[j]) << 16));
}

static inline size_t align_up(size_t v, size_t a) { return (v + a - 1) & ~(a - 1); }

extern "C" void kernel_launch(void* const* d_in, const int* in_sizes, int n_in,
                              void* d_out, int out_size, void* d_ws, size_t ws_size,
                              hipStream_t stream) {
    const float* x    = (const float*)d_in[0];
    const int*   erow = (const int*)d_in[1];
    const int*   ecol = (const int*)d_in[2];
    const float* eval = (const float*)d_in[3];
    const float* W    = (const float*)d_in[4];
    const float* bias = (const float*)d_in[5];
    float* out = (float*)d_out;

    const int n_nodes = in_sizes[0] / D;
    const int n_edges = in_sizes[1];
    const int nb = (n_nodes + NPB - 1) / NPB;

    char* base = (char*)d_ws;
    size_t off = 0;
    unsigned short* supb = (unsigned short*)(base + off); off = align_up(off + (size_t)n_nodes * D * 2, 256);
    int*  gcursor = (int*)(base + off);  off = align_up(off + (size_t)nb * 4, 256);
    int2* coarse  = (int2*)(base + off); off = align_up(off + (size_t)nb * CAP * 8, 256);

    const bool fast = (n_nodes < (1 << 20)) && (nb <= NBMAX) && (off <= ws_size);
    const int gemm_blocks = (n_nodes + 63) / 64;
    const int bin_blocks = fast ? (n_edges + C1 - 1) / C1 : 0;

    if (fast)
        hipMemsetAsync(gcursor, 0, (size_t)nb * 4, stream);

    fused_gemm_bin_kernel<<<bin_blocks + gemm_blocks, 256, 0, stream>>>(
        x, W, erow, ecol, eval, gcursor, coarse, supb,
        n_edges, nb, n_nodes, bin_blocks);

    if (fast) {
        sortgather_kernel<<<nb, BT, 0, stream>>>(
            gcursor, coarse, supb, bias, out, n_nodes);
    } else {
        int total4 = n_nodes * (D / 4);
        init_out_kernel<<<(total4 + 255) / 256, 256, 0, stream>>>(
            (float4*)out, (const float4*)bias, total4);
        scatter_fb_kernel<<<(n_edges + 7) / 8, 256, 0, stream>>>(
            erow, ecol, eval, supb, out, n_edges);
    }
}